// Round 16
// baseline (27929.932 us; speedup 1.0000x reference)
//
#include <hip/hip_runtime.h>
#include <hip/hip_bf16.h>

// NeuralODE Bosh3 — Round 16: 8-way model-parallel, LDS-resident weights,
// sc0/sc1 L3 exchange (r14), with the sync protocol reduced to the
// dependency minimum: PER-WAVE counters, no __syncthreads in the main loop.
// Each wave: work -> vmcnt(0) (wave-local drain) -> lane0 relaxed +1;
// entry gate: poll count >= 32*phase (8 blocks x 4 waves, one add each:
// count>=32p iff ALL waves finished phase p). Removes the 2 barrier-wake
// chains + block-wide drain per phase that made r14/r15 ~6us/phase.

#define B_ 2048
#define L_ 128
#define P_ 8
#define T_ 128
#define GT_ 64                 // batch rows per group
#define NGRP (B_/GT_)          // 32 groups
#define NBLK (NGRP*8)          // 256 blocks

typedef __attribute__((ext_vector_type(8))) short short8;
typedef __attribute__((ext_vector_type(4))) float f32x4;
typedef __attribute__((ext_vector_type(4))) unsigned int u32x4;

// wp layout (ushort units), identical to r13/r14.
#define WTOT (800*512)
#define CNT_OFF (WTOT + 256)        // 32 x u32 sync counters
#define EXB (WTOT + 256 + 64)       // exchange buffers base
#define XSTR 160                    // xbuf row stride (ushorts)
#define GSTR (64*XSTR + 2*64*512)   // per-group: xbuf + h1buf + h2buf

#define VMW0 asm volatile("s_waitcnt vmcnt(0)" ::: "memory")
#define SCHB __builtin_amdgcn_sched_barrier(0)

__device__ __forceinline__ unsigned short f2bf(float f){
  unsigned u = __builtin_bit_cast(unsigned, f);
  u += 0x7fffu + ((u >> 16) & 1u);
  return (unsigned short)(u >> 16);
}

__device__ __forceinline__ float tanh_fast(float x){
  float e = __expf(2.0f * x);
  return 1.0f - __fdividef(2.0f, e + 1.0f);
}

// device-coherent (L3-point) 16B load / 2B store: sc0 sc1 bypass L1+L2
__device__ __forceinline__ short8 ld_dev(const unsigned short* p){
  u32x4 r;
  asm volatile("global_load_dwordx4 %0, %1, off sc0 sc1"
               : "=v"(r) : "v"(p) : "memory");
  return __builtin_bit_cast(short8, r);
}
__device__ __forceinline__ void st_dev16(unsigned short* p, unsigned short v){
  unsigned vv = v;
  asm volatile("global_store_short %0, %1, off sc0 sc1"
               :: "v"(p), "v"(vv) : "memory");
}

__global__ void prep_weights(const float* __restrict__ W0,
                             const float* __restrict__ W1,
                             const float* __restrict__ W2,
                             const float* __restrict__ ts,
                             unsigned short* __restrict__ wp){
  int idx = blockIdx.x * blockDim.x + threadIdx.x;
  if (idx >= WTOT){
    int t = idx - WTOT;
    if (t < T_ - 1){
      float* dts = (float*)(wp + WTOT);
      dts[t] = ts[t+1] - ts[t];
    } else if (t >= 128 && t < 160){
      ((unsigned*)(wp + CNT_OFF))[t - 128] = 0u;   // zeroed every launch
    }
    return;
  }
  int e = idx & 511, f = idx >> 9;
  int j = e & 7, lane = e >> 3;
  int m = f / 100, r = f % 100;
  const float* src; int nt, kt, Korig;
  if (r < 20)      { src = W0; Korig = 136; nt = 4*m + r/5;        kt = r%5; }
  else if (r < 84) { int q = r-20; src = W1; Korig = 512; nt = 4*m + (q>>4); kt = q&15; }
  else             { src = W2; Korig = 512; nt = m;                kt = r-84; }
  int row = nt*16 + (lane & 15);
  int k   = kt*32 + ((lane >> 4) << 3) + j;
  float v = (k < Korig) ? src[row*Korig + k] : 0.0f;
  wp[idx] = f2bf(v);
}

__global__ __launch_bounds__(256, 1)
void ode_main(const float* __restrict__ x0,
              const float* __restrict__ args,
              const float* __restrict__ b0, const float* __restrict__ b1,
              const float* __restrict__ b2,
              unsigned short* wp,
              float* __restrict__ out){
  __shared__ __align__(16) unsigned short wlds[100*512];   // 100 KiB weights
  __shared__ float dtl[T_];

  const int tid  = threadIdx.x;
  const int lane = tid & 63;
  const int wv   = tid >> 6;        // wave 0..3 = row panel
  const int lo   = lane & 15;
  const int hi   = lane >> 4;
  const int bid  = blockIdx.x;
  const int m    = (bid >> 3) & 7;              // member (model slice)
  const int g    = (bid & 7)*4 + (bid >> 6);    // group (XCD-local layout)
  const int r0   = g * GT_;

  unsigned* cnt = (unsigned*)(wp + CNT_OFF) + g;
  unsigned short* gx  = wp + EXB + (size_t)g * GSTR;     // x [64][160]
  unsigned short* h1b = gx  + 64*XSTR;                   // h1 [64][512]
  unsigned short* h2b = h1b + 64*512;                    // h2 [64][512]

  // weights slice -> LDS (once)
  {
    const u32x4* s = (const u32x4*)(wp + (size_t)m * 51200);
    u32x4* d = (u32x4*)wlds;
    for (int i = tid; i < 6400; i += 256) d[i] = s[i];
  }
  if (tid < T_-1) dtl[tid] = ((const float*)(wp + WTOT))[tid];

  float b0v[4], b1v[4];
  #pragma unroll
  for (int n = 0; n < 4; ++n){
    b0v[n] = b0[(4*m + n)*16 + lo];
    b1v[n] = b1[(4*m + n)*16 + lo];
  }
  const int c3 = m*16 + lo;
  float b2v = b2[c3];

  // ODE state: rows wv*16+4hi+j, col c3
  float yr[4], yn[4];
  #pragma unroll
  for (int j = 0; j < 4; ++j){
    int row = wv*16 + 4*hi + j;
    float v = x0[(r0 + row)*L_ + c3];
    yr[j] = v;
    __builtin_nontemporal_store(v, &out[((r0 + row)*T_ + 0)*L_ + c3]);
    st_dev16(gx + row*XSTR + c3, f2bf(v));
  }
  if (m == 0){   // args + zero pad cols 128..159, all 64 rows
    for (int i = tid; i < 64*32; i += 256){
      int row = i >> 5, cc = 128 + (i & 31);
      unsigned short vv = (cc < 136) ? f2bf(args[(r0 + row)*P_ + (cc - 128)])
                                     : (unsigned short)0;
      st_dev16(gx + row*XSTR + cc, vv);
    }
  }
  __syncthreads();   // LDS (wlds, dtl) visible block-wide; only barrier used

  // ---- per-wave sync: no barriers. Each wave adds once per phase.
  unsigned tgt = 32;   // 8 blocks x 4 waves
  auto wsig = [&]{
    VMW0;             // this wave's sc1 stores (and loads) retired to L3
    if (lane == 0)
      __hip_atomic_fetch_add(cnt, 1u, __ATOMIC_RELAXED, __HIP_MEMORY_SCOPE_AGENT);
  };
  auto wwait = [&]{
    unsigned v;
    do {
      v = 0;
      if (lane == 0)
        v = __hip_atomic_load(cnt, __ATOMIC_RELAXED, __HIP_MEMORY_SCOPE_AGENT);
      v = __shfl(v, 0);
      if (v < tgt) __builtin_amdgcn_s_sleep(1);
    } while (v < tgt);
    tgt += 32;
  };

  wsig(); wwait();   // init exchange published

  const int arow = wv*16 + lo;   // per-lane A-frag source row
  const int aoff = hi << 3;      // per-lane k sub-offset (ushorts)

  auto evalf = [&](f32x4& dacc){
    // ---- layer 1: A from gx (L3), B = W0 slice (LDS)
    short8 xa[5];
    #pragma unroll
    for (int kt = 0; kt < 5; ++kt)
      xa[kt] = ld_dev(gx + arow*XSTR + kt*32 + aoff);
    VMW0; SCHB;
    f32x4 acc[4];
    #pragma unroll
    for (int n = 0; n < 4; ++n) acc[n] = f32x4{0,0,0,0};
    #pragma unroll
    for (int kt = 0; kt < 5; ++kt)
      #pragma unroll
      for (int n = 0; n < 4; ++n){
        short8 wf = *(const short8*)(wlds + (n*5 + kt)*512 + lane*8);
        acc[n] = __builtin_amdgcn_mfma_f32_16x16x32_bf16(xa[kt], wf, acc[n], 0, 0, 0);
      }
    #pragma unroll
    for (int n = 0; n < 4; ++n)
      #pragma unroll
      for (int j = 0; j < 4; ++j)
        st_dev16(h1b + (wv*16 + 4*hi + j)*512 + (4*m + n)*16 + lo,
                 f2bf(tanh_fast(acc[n][j] + b0v[n])));
    wsig(); wwait();
    // ---- layer 2: A from h1b (L3), B = W1 slice (LDS)
    short8 ha[16];
    #pragma unroll
    for (int kt = 0; kt < 16; ++kt)
      ha[kt] = ld_dev(h1b + arow*512 + kt*32 + aoff);
    VMW0; SCHB;
    #pragma unroll
    for (int n = 0; n < 4; ++n) acc[n] = f32x4{0,0,0,0};
    #pragma unroll
    for (int kt = 0; kt < 16; ++kt)
      #pragma unroll
      for (int n = 0; n < 4; ++n){
        short8 wf = *(const short8*)(wlds + (20 + n*16 + kt)*512 + lane*8);
        acc[n] = __builtin_amdgcn_mfma_f32_16x16x32_bf16(ha[kt], wf, acc[n], 0, 0, 0);
      }
    #pragma unroll
    for (int n = 0; n < 4; ++n)
      #pragma unroll
      for (int j = 0; j < 4; ++j)
        st_dev16(h2b + (wv*16 + 4*hi + j)*512 + (4*m + n)*16 + lo,
                 f2bf(tanh_fast(acc[n][j] + b1v[n])));
    wsig(); wwait();
    // ---- layer 3: A from h2b (L3), B = W2 slice (LDS)
    short8 h2a[16];
    #pragma unroll
    for (int kt = 0; kt < 16; ++kt)
      h2a[kt] = ld_dev(h2b + arow*512 + kt*32 + aoff);
    VMW0; SCHB;
    f32x4 a3 = f32x4{0,0,0,0};
    #pragma unroll
    for (int kt = 0; kt < 16; ++kt){
      short8 wf = *(const short8*)(wlds + (84 + kt)*512 + lane*8);
      a3 = __builtin_amdgcn_mfma_f32_16x16x32_bf16(h2a[kt], wf, a3, 0, 0, 0);
    }
    dacc = a3;
  };

  // Bosh3: k1=f(y); k2=f(y+dt/2 k1); k3=f(y+3dt/4 k2); y+=dt(2/9k1+1/3k2+4/9k3)
  for (int t = 1; t < T_; ++t){
    float dt = dtl[t-1];
    f32x4 d;

    evalf(d);                              // k1
    #pragma unroll
    for (int j = 0; j < 4; ++j){
      float k = d[j] + b2v;
      yn[j] = yr[j] + dt*(2.0f/9.0f)*k;
      float xs = yr[j] + 0.5f*dt*k;
      st_dev16(gx + (wv*16 + 4*hi + j)*XSTR + c3, f2bf(xs));
    }
    wsig(); wwait();

    evalf(d);                              // k2
    #pragma unroll
    for (int j = 0; j < 4; ++j){
      float k = d[j] + b2v;
      yn[j] += dt*(1.0f/3.0f)*k;
      float xs = yr[j] + 0.75f*dt*k;
      st_dev16(gx + (wv*16 + 4*hi + j)*XSTR + c3, f2bf(xs));
    }
    wsig(); wwait();

    evalf(d);                              // k3
    #pragma unroll
    for (int j = 0; j < 4; ++j){
      float k = d[j] + b2v;
      yn[j] += dt*(4.0f/9.0f)*k;
      yr[j] = yn[j];
      int row = wv*16 + 4*hi + j;
      st_dev16(gx + row*XSTR + c3, f2bf(yr[j]));
      __builtin_nontemporal_store(yr[j], &out[((r0 + row)*T_ + t)*L_ + c3]);
    }
    wsig(); wwait();
  }
}

extern "C" void kernel_launch(void* const* d_in, const int* in_sizes, int n_in,
                              void* d_out, int out_size, void* d_ws, size_t ws_size,
                              hipStream_t stream) {
  const float* x0   = (const float*)d_in[0];
  const float* ts   = (const float*)d_in[1];
  const float* args = (const float*)d_in[2];
  const float* W0   = (const float*)d_in[3];
  const float* b0   = (const float*)d_in[4];
  const float* W1   = (const float*)d_in[5];
  const float* b1   = (const float*)d_in[6];
  const float* W2   = (const float*)d_in[7];
  const float* b2   = (const float*)d_in[8];
  unsigned short* wp = (unsigned short*)d_ws;
  float* out = (float*)d_out;

  prep_weights<<<(WTOT + 160 + 255)/256, 256, 0, stream>>>(W0, W1, W2, ts, wp);
  ode_main<<<NBLK, 256, 0, stream>>>(x0, args, b0, b1, b2, wp, out);
}

// Round 18
// 4643.047 us; speedup vs baseline: 6.0154x; 6.0154x over previous
//
#include <hip/hip_runtime.h>
#include <hip/hip_bf16.h>

// NeuralODE Bosh3 — Round 18: r17 with the h-publish coverage bug fixed.
// 8-way model-parallel, LDS-resident weights, sc0/sc1 L3 exchange,
// per-PANEL counters (8 adds + 8 pollers each), no barriers in main loop,
// coalesced publish via LDS stage (now TWO 16B stores per lane = full 2KB),
// out nt-stores overlapped with the poll.

#define B_ 2048
#define L_ 128
#define P_ 8
#define T_ 128
#define GT_ 64
#define NGRP (B_/GT_)          // 32 groups
#define NBLK (NGRP*8)          // 256 blocks

typedef __attribute__((ext_vector_type(8))) short short8;
typedef __attribute__((ext_vector_type(4))) float f32x4;
typedef __attribute__((ext_vector_type(4))) unsigned int u32x4;

// wp layout (ushort units), weights as r13/r14 (member-major, 100 frags each)
#define WTOT (800*512)
#define CNT_OFF (WTOT + 256)            // 128 counters x 64 u32 spacing
#define EXB (CNT_OFF + 16384)           // exchange buffers base
#define XSTR 160
#define GSTR (64*XSTR + 2*64*512)

#define VMW0 asm volatile("s_waitcnt vmcnt(0)" ::: "memory")
#define LKW0 asm volatile("s_waitcnt lgkmcnt(0)" ::: "memory")
#define SCHB __builtin_amdgcn_sched_barrier(0)

__device__ __forceinline__ unsigned short f2bf(float f){
  unsigned u = __builtin_bit_cast(unsigned, f);
  u += 0x7fffu + ((u >> 16) & 1u);
  return (unsigned short)(u >> 16);
}

__device__ __forceinline__ float tanh_fast(float x){
  float e = __expf(2.0f * x);
  return 1.0f - __fdividef(2.0f, e + 1.0f);
}

__device__ __forceinline__ short8 ld_dev(const unsigned short* p){
  u32x4 r;
  asm volatile("global_load_dwordx4 %0, %1, off sc0 sc1"
               : "=v"(r) : "v"(p) : "memory");
  return __builtin_bit_cast(short8, r);
}
__device__ __forceinline__ void st_dev16b(unsigned short* p, u32x4 v){
  asm volatile("global_store_dwordx4 %0, %1, off sc0 sc1"
               :: "v"(p), "v"(v) : "memory");
}
__device__ __forceinline__ void st_dev2(unsigned short* p, unsigned short v){
  unsigned vv = v;
  asm volatile("global_store_short %0, %1, off sc0 sc1"
               :: "v"(p), "v"(vv) : "memory");
}

__global__ void prep_weights(const float* __restrict__ W0,
                             const float* __restrict__ W1,
                             const float* __restrict__ W2,
                             const float* __restrict__ ts,
                             unsigned short* __restrict__ wp){
  int idx = blockIdx.x * blockDim.x + threadIdx.x;
  if (idx >= WTOT){
    int t = idx - WTOT;
    if (t < T_ - 1){
      float* dts = (float*)(wp + WTOT);
      dts[t] = ts[t+1] - ts[t];
    } else if (t >= T_ && t < T_ + 8192){
      ((unsigned*)(wp + CNT_OFF))[t - T_] = 0u;    // zero 128 counters+pad
    }
    return;
  }
  int e = idx & 511, f = idx >> 9;
  int j = e & 7, lane = e >> 3;
  int m = f / 100, r = f % 100;
  const float* src; int nt, kt, Korig;
  if (r < 20)      { src = W0; Korig = 136; nt = 4*m + r/5;        kt = r%5; }
  else if (r < 84) { int q = r-20; src = W1; Korig = 512; nt = 4*m + (q>>4); kt = q&15; }
  else             { src = W2; Korig = 512; nt = m;                kt = r-84; }
  int row = nt*16 + (lane & 15);
  int k   = kt*32 + ((lane >> 4) << 3) + j;
  float v = (k < Korig) ? src[row*Korig + k] : 0.0f;
  wp[idx] = f2bf(v);
}

__global__ __launch_bounds__(256, 1)
void ode_main(const float* __restrict__ x0,
              const float* __restrict__ args,
              const float* __restrict__ b0, const float* __restrict__ b1,
              const float* __restrict__ b2,
              unsigned short* wp,
              float* __restrict__ out){
  __shared__ __align__(16) unsigned short wlds[100*512];   // 100 KiB
  __shared__ __align__(16) unsigned short hstg[4][16][64]; // 8 KiB stage
  __shared__ float dtl[T_];

  const int tid  = threadIdx.x;
  const int lane = tid & 63;
  const int wv   = tid >> 6;        // wave 0..3 = row panel
  const int lo   = lane & 15;
  const int hi   = lane >> 4;
  const int bid  = blockIdx.x;
  const int m    = (bid >> 3) & 7;              // member (model slice)
  const int g    = (bid & 7)*4 + (bid >> 6);    // group (XCD-local-ish)
  const int r0   = g * GT_;

  unsigned* cnt = (unsigned*)(wp + CNT_OFF) + (g*4 + wv)*64;
  unsigned short* gx  = wp + EXB + (size_t)g * GSTR;     // x [64][160]
  unsigned short* h1b = gx  + 64*XSTR;                   // h1 [64][512]
  unsigned short* h2b = h1b + 64*512;                    // h2 [64][512]

  // weights slice -> LDS (once)
  {
    const u32x4* s = (const u32x4*)(wp + (size_t)m * 51200);
    u32x4* d = (u32x4*)wlds;
    for (int i = tid; i < 6400; i += 256) d[i] = s[i];
  }
  if (tid < T_-1) dtl[tid] = ((const float*)(wp + WTOT))[tid];

  float b0v[4], b1v[4];
  #pragma unroll
  for (int n = 0; n < 4; ++n){
    b0v[n] = b0[(4*m + n)*16 + lo];
    b1v[n] = b1[(4*m + n)*16 + lo];
  }
  const int c3 = m*16 + lo;
  float b2v = b2[c3];

  // ODE state: rows wv*16+4hi+j, col c3 (panel-local)
  float yr[4], yn[4];
  #pragma unroll
  for (int j = 0; j < 4; ++j){
    int row = wv*16 + 4*hi + j;
    float v = x0[(r0 + row)*L_ + c3];
    yr[j] = v;
    __builtin_nontemporal_store(v, &out[((r0 + row)*T_ + 0)*L_ + c3]);
    st_dev2(gx + row*XSTR + c3, f2bf(v));
  }
  if (m == 0){   // args + zero pad cols 128..159, panel-local rows
    #pragma unroll
    for (int e = 0; e < 8; ++e){
      int idx = lane*8 + e;              // 512 = 16 rows x 32 cols
      int row = wv*16 + (idx >> 5), cc = 128 + (idx & 31);
      unsigned short vv = (cc < 136) ? f2bf(args[(r0 + row)*P_ + (cc - 128)])
                                     : (unsigned short)0;
      st_dev2(gx + row*XSTR + cc, vv);
    }
  }
  __syncthreads();   // LDS (wlds, dtl) visible; only barrier in the kernel

  unsigned tgt = 8;
  auto sigpoll = [&]{
    // precondition: VMW0 already done (stores at L3)
    if (lane == 0)
      __hip_atomic_fetch_add(cnt, 1u, __ATOMIC_RELAXED, __HIP_MEMORY_SCOPE_AGENT);
    unsigned v;
    do {
      v = 0;
      if (lane == 0)
        v = __hip_atomic_load(cnt, __ATOMIC_RELAXED, __HIP_MEMORY_SCOPE_AGENT);
      v = __shfl(v, 0);
      if (v < tgt) __builtin_amdgcn_s_sleep(1);
    } while (v < tgt);
    tgt += 8;
  };

  VMW0;
  sigpoll();   // init exchange published (panel-gated)

  const int arow = wv*16 + lo;
  const int aoff = hi << 3;
  const int r16 = lane >> 2, ch4 = lane & 3;         // h publish: row, col-grp
  const int xr16 = (lane & 31) >> 1, xch = lane & 1; // x publish lanes (0..31)

  // publish member's 64-col slice of h (2KB/wave = 64 lanes x 2 x 16B)
  auto publish_h = [&](unsigned short* hb){
    LKW0;
    u32x4 v0 = *(const u32x4*)&hstg[wv][r16][ch4*16];
    u32x4 v1 = *(const u32x4*)&hstg[wv][r16][ch4*16 + 8];
    unsigned short* dst = hb + (wv*16 + r16)*512 + m*64 + ch4*16;
    st_dev16b(dst, v0);
    st_dev16b(dst + 8, v1);
    VMW0;
  };

  auto phase1 = [&]{
    short8 xa[5];
    #pragma unroll
    for (int kt = 0; kt < 5; ++kt)
      xa[kt] = ld_dev(gx + arow*XSTR + kt*32 + aoff);
    VMW0; SCHB;
    f32x4 acc[4];
    #pragma unroll
    for (int n = 0; n < 4; ++n) acc[n] = f32x4{0,0,0,0};
    #pragma unroll
    for (int kt = 0; kt < 5; ++kt)
      #pragma unroll
      for (int n = 0; n < 4; ++n){
        short8 wf = *(const short8*)(wlds + (n*5 + kt)*512 + lane*8);
        acc[n] = __builtin_amdgcn_mfma_f32_16x16x32_bf16(xa[kt], wf, acc[n], 0, 0, 0);
      }
    #pragma unroll
    for (int n = 0; n < 4; ++n)
      #pragma unroll
      for (int j = 0; j < 4; ++j)
        hstg[wv][4*hi + j][n*16 + lo] = f2bf(tanh_fast(acc[n][j] + b0v[n]));
    publish_h(h1b);
    sigpoll();
  };

  auto phase2 = [&]{
    short8 ha[16];
    #pragma unroll
    for (int kt = 0; kt < 16; ++kt)
      ha[kt] = ld_dev(h1b + arow*512 + kt*32 + aoff);
    VMW0; SCHB;
    f32x4 acc[4];
    #pragma unroll
    for (int n = 0; n < 4; ++n) acc[n] = f32x4{0,0,0,0};
    #pragma unroll
    for (int kt = 0; kt < 16; ++kt)
      #pragma unroll
      for (int n = 0; n < 4; ++n){
        short8 wf = *(const short8*)(wlds + (20 + n*16 + kt)*512 + lane*8);
        acc[n] = __builtin_amdgcn_mfma_f32_16x16x32_bf16(ha[kt], wf, acc[n], 0, 0, 0);
      }
    #pragma unroll
    for (int n = 0; n < 4; ++n)
      #pragma unroll
      for (int j = 0; j < 4; ++j)
        hstg[wv][4*hi + j][n*16 + lo] = f2bf(tanh_fast(acc[n][j] + b1v[n]));
    publish_h(h2b);
    sigpoll();
  };

  // Bosh3: k1=f(y); k2=f(y+dt/2 k1); k3=f(y+3dt/4 k2); y+=dt(2/9k1+1/3k2+4/9k3)
  for (int t = 1; t < T_; ++t){
    float dt = dtl[t-1];
    #pragma unroll 1
    for (int s = 0; s < 3; ++s){
      phase1();
      phase2();
      // phase3: layer 3 + state update + x publish
      short8 h2a[16];
      #pragma unroll
      for (int kt = 0; kt < 16; ++kt)
        h2a[kt] = ld_dev(h2b + arow*512 + kt*32 + aoff);
      VMW0; SCHB;
      f32x4 a3 = f32x4{0,0,0,0};
      #pragma unroll
      for (int kt = 0; kt < 16; ++kt){
        short8 wf = *(const short8*)(wlds + (84 + kt)*512 + lane*8);
        a3 = __builtin_amdgcn_mfma_f32_16x16x32_bf16(h2a[kt], wf, a3, 0, 0, 0);
      }
      #pragma unroll
      for (int j = 0; j < 4; ++j){
        float k = a3[j] + b2v;
        float xs;
        if (s == 0){ yn[j] = yr[j] + dt*(2.0f/9.0f)*k; xs = yr[j] + 0.5f*dt*k; }
        else if (s == 1){ yn[j] += dt*(1.0f/3.0f)*k;   xs = yr[j] + 0.75f*dt*k; }
        else { yn[j] += dt*(4.0f/9.0f)*k; yr[j] = yn[j]; xs = yr[j]; }
        hstg[wv][4*hi + j][lo] = f2bf(xs);
      }
      LKW0;
      if (lane < 32){   // coalesced x publish: 16 rows x 16 cols x 2B
        u32x4 v = *(const u32x4*)&hstg[wv][xr16][xch*8];
        st_dev16b(gx + (wv*16 + xr16)*XSTR + m*16 + xch*8, v);
      }
      VMW0;
      if (lane == 0)
        __hip_atomic_fetch_add(cnt, 1u, __ATOMIC_RELAXED, __HIP_MEMORY_SCOPE_AGENT);
      if (s == 2){      // out store overlaps the poll (not a sync dependency)
        #pragma unroll
        for (int j = 0; j < 4; ++j){
          int row = wv*16 + 4*hi + j;
          __builtin_nontemporal_store(yr[j], &out[((r0 + row)*T_ + t)*L_ + c3]);
        }
      }
      {
        unsigned v;
        do {
          v = 0;
          if (lane == 0)
            v = __hip_atomic_load(cnt, __ATOMIC_RELAXED, __HIP_MEMORY_SCOPE_AGENT);
          v = __shfl(v, 0);
          if (v < tgt) __builtin_amdgcn_s_sleep(1);
        } while (v < tgt);
        tgt += 8;
      }
    }
  }
}

extern "C" void kernel_launch(void* const* d_in, const int* in_sizes, int n_in,
                              void* d_out, int out_size, void* d_ws, size_t ws_size,
                              hipStream_t stream) {
  const float* x0   = (const float*)d_in[0];
  const float* ts   = (const float*)d_in[1];
  const float* args = (const float*)d_in[2];
  const float* W0   = (const float*)d_in[3];
  const float* b0   = (const float*)d_in[4];
  const float* W1   = (const float*)d_in[5];
  const float* b1   = (const float*)d_in[6];
  const float* W2   = (const float*)d_in[7];
  const float* b2   = (const float*)d_in[8];
  unsigned short* wp = (unsigned short*)d_ws;   // ~5.6 MB used
  float* out = (float*)d_out;

  prep_weights<<<(WTOT + T_ + 8192 + 255)/256, 256, 0, stream>>>(W0, W1, W2, ts, wp);
  ode_main<<<NBLK, 256, 0, stream>>>(x0, args, b0, b1, b2, wp, out);
}